// Round 1
// baseline (588.500 us; speedup 1.0000x reference)
//
#include <hip/hip_runtime.h>

// CSSM TinyViT block, fused bf16-MFMA implementation for gfx950.
// B=16,H=32,W=32 -> 16384 rows of C=384. T=8, HID=1536.

#define CCH   384
#define NPIX  16384
#define BMROWS 64
#define NTHR  512          // 8 waves: 2 (M) x 4 (N)
#define LNEPS 1e-6f

typedef __attribute__((ext_vector_type(8))) short bf8_t;   // 8 x bf16
typedef __attribute__((ext_vector_type(4))) float f4_t;    // 4 x f32
typedef __attribute__((ext_vector_type(8))) unsigned short us8_t;

// workspace offsets (ushort units). Each 16x16x32 B-tile = 512 bf16 = 1KB.
// tiles(K,N) = (K/32)*(N/16); order: tile = n16*(K/32) + kb
#define OFF_WU 0u
#define OFF_WG 147456u      // 288 tiles * 512
#define OFF_A  294912u
#define OFF_W1 442368u      // 384x1536 -> 1152 tiles
#define OFF_W2 1032192u     // 1536x384 -> 1152 tiles
// total 1622016 ushorts = 3.1 MB of d_ws

__device__ __forceinline__ unsigned short f2bf(float f) {
  union { float f; unsigned u; } x; x.f = f;
  unsigned r = (x.u >> 16) & 1u;
  return (unsigned short)((x.u + 0x7fffu + r) >> 16);   // RNE
}
__device__ __forceinline__ float bf2f(unsigned short h) {
  union { unsigned u; float f; } x; x.u = ((unsigned)h) << 16;
  return x.f;
}

// Pack f32 W (K x N, row-major) into bf16 MFMA-B fragment order:
// P[tile*512 + lane*8 + j] = W[kb*32 + (lane>>4)*8 + j][n16*16 + (lane&15)]
__global__ void pack_w(const float* __restrict__ W, unsigned short* __restrict__ P,
                       int K, int N) {
  const int nkb = K >> 5;
  const int total = (nkb * (N >> 4)) << 6;
  const int gid = blockIdx.x * blockDim.x + threadIdx.x;
  if (gid >= total) return;
  const int tile = gid >> 6, l = gid & 63;
  const int kb = tile % nkb, n16 = tile / nkb;
  const int krow = kb * 32 + ((l >> 4) << 3);
  const int col = n16 * 16 + (l & 15);
  us8_t pk;
  #pragma unroll
  for (int j = 0; j < 8; ++j) pk[j] = f2bf(W[(size_t)(krow + j) * N + col]);
  *reinterpret_cast<us8_t*>(P + ((size_t)tile << 9) + (l << 3)) = pk;
}

// acc[2][6] += A(LDS rows mw*32..mw*32+31, swizzled) * B(packed tiles)
// A-frag: lane l -> row (l&15)+16*mt, k = kb*32 + (l>>4)*8 + j
// B-frag: lane l -> col (l&15)+16*nt, same k grouping (pre-packed)
__device__ __forceinline__ void gemm_acc(const unsigned short* sb,
                                         const unsigned short* __restrict__ bp,
                                         int kb0, int nkb, int n16base,
                                         int mw, int lane, f4_t acc[2][6]) {
  const int ar0 = mw * 32 + (lane & 15);
  const int ar1 = ar0 + 16;
  const int sw  = (ar0 & 7) << 3;        // (ar1&7)==(ar0&7)
  const int koff = (lane >> 4) << 3;
  #pragma unroll
  for (int kb = 0; kb < 12; ++kb) {
    const int ac = kb * 32 + koff;
    const bf8_t a0 = *reinterpret_cast<const bf8_t*>(&sb[ar0 * CCH + (ac ^ sw)]);
    const bf8_t a1 = *reinterpret_cast<const bf8_t*>(&sb[ar1 * CCH + (ac ^ sw)]);
    #pragma unroll
    for (int nt = 0; nt < 6; ++nt) {
      const bf8_t b = *reinterpret_cast<const bf8_t*>(
          &bp[(((size_t)(n16base + nt) * nkb + (kb0 + kb)) << 9) + (lane << 3)]);
      acc[0][nt] = __builtin_amdgcn_mfma_f32_16x16x32_bf16(a0, b, acc[0][nt], 0, 0, 0);
      acc[1][nt] = __builtin_amdgcn_mfma_f32_16x16x32_bf16(a1, b, acc[1][nt], 0, 0, 0);
    }
  }
}

// write C/D-layout tile (f32 regs) into swizzled bf16 LDS buffer
__device__ __forceinline__ void write_tile(unsigned short* sb, const f4_t t[2][6],
                                           int mw, int nw, int lane) {
  const int cb = nw * 96 + (lane & 15);
  #pragma unroll
  for (int mt = 0; mt < 2; ++mt)
    #pragma unroll
    for (int j = 0; j < 4; ++j) {
      const int row = mw * 32 + mt * 16 + ((lane >> 4) << 2) + j;
      const int sw = (row & 7) << 3;
      #pragma unroll
      for (int nt = 0; nt < 6; ++nt)
        sb[row * CCH + ((cb + nt * 16) ^ sw)] = f2bf(t[mt][nt][j]);
    }
}

__device__ __forceinline__ void zero_acc(f4_t a[2][6]) {
  #pragma unroll
  for (int mt = 0; mt < 2; ++mt)
    #pragma unroll
    for (int nt = 0; nt < 6; ++nt) a[mt][nt] = (f4_t){0.f, 0.f, 0.f, 0.f};
}

__global__ __launch_bounds__(NTHR, 2) void cssm_main(
    const float* __restrict__ x,
    const float* __restrict__ n1s, const float* __restrict__ n1b,
    const float* __restrict__ bu, const float* __restrict__ bg,
    const float* __restrict__ n2s, const float* __restrict__ n2b,
    const float* __restrict__ b1, const float* __restrict__ b2,
    const unsigned short* __restrict__ wp,
    float* __restrict__ out) {
  __shared__ unsigned short sbuf[BMROWS * CCH];   // 48 KB, xn -> h -> x1/xn2 -> m
  __shared__ float srow[2 * BMROWS];              // LN2 mu, rs

  const int tid = threadIdx.x;
  const int lane = tid & 63;
  const int wv = tid >> 6;
  const int mw = wv >> 2, nw = wv & 3;            // wave tile: 32 rows x 96 cols
  const int r0 = blockIdx.x * BMROWS;

  // ---------------- Phase A: LN1 -> sbuf (bf16, swizzled) ----------------
  {
    const int row = tid >> 3, seg = tid & 7;      // 8 threads / row, 48 elems each
    const float* xr = x + (size_t)(r0 + row) * CCH + seg * 48;
    float v[48];
    float s = 0.f, s2 = 0.f;
    #pragma unroll
    for (int i = 0; i < 12; ++i) {
      const f4_t t = reinterpret_cast<const f4_t*>(xr)[i];
      #pragma unroll
      for (int j = 0; j < 4; ++j) { const float f = t[j]; v[i * 4 + j] = f; s += f; s2 += f * f; }
    }
    #pragma unroll
    for (int o = 1; o < 8; o <<= 1) { s += __shfl_xor(s, o, 64); s2 += __shfl_xor(s2, o, 64); }
    const float mu = s * (1.f / CCH);
    const float rs = rsqrtf(fmaxf(s2 * (1.f / CCH) - mu * mu, 0.f) + LNEPS);
    const int sw = (row & 7) << 3;
    #pragma unroll
    for (int g8 = 0; g8 < 6; ++g8) {
      us8_t pk;
      #pragma unroll
      for (int j = 0; j < 8; ++j) {
        const int colc = seg * 48 + g8 * 8 + j;
        pk[j] = f2bf((v[g8 * 8 + j] - mu) * rs * n1s[colc] + n1b[colc]);
      }
      *reinterpret_cast<us8_t*>(&sbuf[row * CCH + ((seg * 48 + g8 * 8) ^ sw)]) = pk;
    }
  }
  __syncthreads();

  f4_t acc[2][6], g4[2][6], c4[2][6];

  // ---------------- Phase A2: g = sigmoid(xn@Wg + bg), c = (1-g)*(xn@Wu + bu) ----
  zero_acc(acc);
  gemm_acc(sbuf, wp + OFF_WG, 0, 12, nw * 6, mw, lane, acc);
  #pragma unroll
  for (int nt = 0; nt < 6; ++nt) {
    const float bgv = bg[nw * 96 + nt * 16 + (lane & 15)];
    #pragma unroll
    for (int mt = 0; mt < 2; ++mt)
      #pragma unroll
      for (int j = 0; j < 4; ++j) {
        const float z = acc[mt][nt][j] + bgv;
        g4[mt][nt][j] = 1.f / (1.f + expf(-z));
      }
  }
  zero_acc(acc);
  gemm_acc(sbuf, wp + OFF_WU, 0, 12, nw * 6, mw, lane, acc);
  #pragma unroll
  for (int nt = 0; nt < 6; ++nt) {
    const float buv = bu[nw * 96 + nt * 16 + (lane & 15)];
    #pragma unroll
    for (int mt = 0; mt < 2; ++mt)
      #pragma unroll
      for (int j = 0; j < 4; ++j)
        c4[mt][nt][j] = (1.f - g4[mt][nt][j]) * (acc[mt][nt][j] + buv);
  }

  // ---------------- Phase B: recurrence h_{t+1} = g * (h_t @ A) + c --------------
  __syncthreads();                 // all waves done reading xn
  write_tile(sbuf, c4, mw, nw, lane);   // h1 = c  (h0 = 0)
  __syncthreads();
  #pragma unroll 1
  for (int stp = 0; stp < 7; ++stp) {   // steps 2..8
    zero_acc(acc);
    gemm_acc(sbuf, wp + OFF_A, 0, 12, nw * 6, mw, lane, acc);
    #pragma unroll
    for (int mt = 0; mt < 2; ++mt)
      #pragma unroll
      for (int nt = 0; nt < 6; ++nt)
        #pragma unroll
        for (int j = 0; j < 4; ++j)
          acc[mt][nt][j] = g4[mt][nt][j] * acc[mt][nt][j] + c4[mt][nt][j];
    __syncthreads();               // reads of h done before overwrite
    if (stp < 6) { write_tile(sbuf, acc, mw, nw, lane); __syncthreads(); }
  }

  // ---------------- Phase C: x1 = x + h; LN2 -> xn2 in sbuf ----------------------
  f4_t x14[2][6];
  #pragma unroll
  for (int mt = 0; mt < 2; ++mt)
    #pragma unroll
    for (int j = 0; j < 4; ++j) {
      const int row = mw * 32 + mt * 16 + ((lane >> 4) << 2) + j;
      #pragma unroll
      for (int nt = 0; nt < 6; ++nt) {
        const int col = nw * 96 + nt * 16 + (lane & 15);
        x14[mt][nt][j] = x[(size_t)(r0 + row) * CCH + col] + acc[mt][nt][j];
      }
    }
  write_tile(sbuf, x14, mw, nw, lane);   // x1 (bf16) for LN2 stats
  __syncthreads();
  {
    const int row = tid >> 3, seg = tid & 7;
    const int sw = (row & 7) << 3;
    float v[48];
    float s = 0.f, s2 = 0.f;
    #pragma unroll
    for (int g8 = 0; g8 < 6; ++g8) {
      const us8_t t = *reinterpret_cast<const us8_t*>(&sbuf[row * CCH + ((seg * 48 + g8 * 8) ^ sw)]);
      #pragma unroll
      for (int j = 0; j < 8; ++j) { const float f = bf2f(t[j]); v[g8 * 8 + j] = f; s += f; s2 += f * f; }
    }
    #pragma unroll
    for (int o = 1; o < 8; o <<= 1) { s += __shfl_xor(s, o, 64); s2 += __shfl_xor(s2, o, 64); }
    const float mu = s * (1.f / CCH);
    const float rs = rsqrtf(fmaxf(s2 * (1.f / CCH) - mu * mu, 0.f) + LNEPS);
    if (seg == 0) { srow[row] = mu; srow[64 + row] = rs; }
    #pragma unroll
    for (int g8 = 0; g8 < 6; ++g8) {
      us8_t pk;
      #pragma unroll
      for (int j = 0; j < 8; ++j) {
        const int colc = seg * 48 + g8 * 8 + j;
        pk[j] = f2bf((v[g8 * 8 + j] - mu) * rs * n2s[colc] + n2b[colc]);
      }
      *reinterpret_cast<us8_t*>(&sbuf[row * CCH + ((seg * 48 + g8 * 8) ^ sw)]) = pk;
    }
  }
  __syncthreads();

  // ---------------- Phase D: MLP in 4 HID-chunks of 384 --------------------------
  float sc2[6], bs2[6];
  #pragma unroll
  for (int nt = 0; nt < 6; ++nt) {
    const int colc = nw * 96 + nt * 16 + (lane & 15);
    sc2[nt] = n2s[colc]; bs2[nt] = n2b[colc];
  }
  f4_t aco[2][6];
  zero_acc(aco);
  #pragma unroll 1
  for (int ch = 0; ch < 4; ++ch) {
    if (ch > 0) {          // regenerate xn2 into sbuf from x1 regs + row stats
      #pragma unroll
      for (int mt = 0; mt < 2; ++mt)
        #pragma unroll
        for (int j = 0; j < 4; ++j) {
          const int row = mw * 32 + mt * 16 + ((lane >> 4) << 2) + j;
          const float mu = srow[row], rs = srow[64 + row];
          const int sw = (row & 7) << 3;
          #pragma unroll
          for (int nt = 0; nt < 6; ++nt) {
            const int col = nw * 96 + nt * 16 + (lane & 15);
            sbuf[row * CCH + (col ^ sw)] = f2bf((x14[mt][nt][j] - mu) * rs * sc2[nt] + bs2[nt]);
          }
        }
      __syncthreads();
    }
    f4_t am[2][6];
    zero_acc(am);
    gemm_acc(sbuf, wp + OFF_W1, 0, 12, ch * 24 + nw * 6, mw, lane, am);
    #pragma unroll
    for (int nt = 0; nt < 6; ++nt) {
      const float b1v = b1[ch * 384 + nw * 96 + nt * 16 + (lane & 15)];
      #pragma unroll
      for (int mt = 0; mt < 2; ++mt)
        #pragma unroll
        for (int j = 0; j < 4; ++j) {
          const float z = am[mt][nt][j] + b1v;
          const float zc = z + 0.044715f * z * z * z;          // tanh-approx GELU (jax default)
          am[mt][nt][j] = 0.5f * z * (1.f + tanhf(0.7978845608028654f * zc));
        }
    }
    __syncthreads();
    write_tile(sbuf, am, mw, nw, lane);
    __syncthreads();
    gemm_acc(sbuf, wp + OFF_W2, ch * 12, 48, nw * 6, mw, lane, aco);
    __syncthreads();     // before next chunk overwrites sbuf
  }

  // ---------------- Phase E: out = x1 + mlp + b2 ---------------------------------
  #pragma unroll
  for (int nt = 0; nt < 6; ++nt) {
    const int col = nw * 96 + nt * 16 + (lane & 15);
    const float b2v = b2[col];
    #pragma unroll
    for (int mt = 0; mt < 2; ++mt)
      #pragma unroll
      for (int j = 0; j < 4; ++j) {
        const int row = mw * 32 + mt * 16 + ((lane >> 4) << 2) + j;
        out[(size_t)(r0 + row) * CCH + col] = x14[mt][nt][j] + aco[mt][nt][j] + b2v;
      }
  }
}

extern "C" void kernel_launch(void* const* d_in, const int* in_sizes, int n_in,
                              void* d_out, int out_size, void* d_ws, size_t ws_size,
                              hipStream_t stream) {
  const float* x   = (const float*)d_in[0];
  const float* n1s = (const float*)d_in[1];
  const float* n1b = (const float*)d_in[2];
  const float* Wu  = (const float*)d_in[3];
  const float* bu  = (const float*)d_in[4];
  const float* Wg  = (const float*)d_in[5];
  const float* bg  = (const float*)d_in[6];
  const float* A   = (const float*)d_in[7];
  const float* n2s = (const float*)d_in[8];
  const float* n2b = (const float*)d_in[9];
  const float* W1  = (const float*)d_in[10];
  const float* b1  = (const float*)d_in[11];
  const float* W2  = (const float*)d_in[12];
  const float* b2  = (const float*)d_in[13];
  unsigned short* wp = (unsigned short*)d_ws;
  float* out = (float*)d_out;

  // pack all weights to bf16 fragment order (runs every call; deterministic)
  {
    int total;
    total = (384 / 32) * (384 / 16) * 64;
    pack_w<<<(total + 255) / 256, 256, 0, stream>>>(Wu, wp + OFF_WU, 384, 384);
    pack_w<<<(total + 255) / 256, 256, 0, stream>>>(Wg, wp + OFF_WG, 384, 384);
    pack_w<<<(total + 255) / 256, 256, 0, stream>>>(A,  wp + OFF_A,  384, 384);
    total = (384 / 32) * (1536 / 16) * 64;
    pack_w<<<(total + 255) / 256, 256, 0, stream>>>(W1, wp + OFF_W1, 384, 1536);
    total = (1536 / 32) * (384 / 16) * 64;
    pack_w<<<(total + 255) / 256, 256, 0, stream>>>(W2, wp + OFF_W2, 1536, 384);
  }

  cssm_main<<<NPIX / BMROWS, NTHR, 0, stream>>>(
      x, n1s, n1b, bu, bg, n2s, n2b, b1, b2, wp, out);
}

// Round 2
// 518.914 us; speedup vs baseline: 1.1341x; 1.1341x over previous
//
#include <hip/hip_runtime.h>

// CSSM TinyViT block, fused bf16-MFMA implementation for gfx950.
// B=16,H=32,W=32 -> 16384 rows of C=384. T=8, HID=1536.
// Round 2: fix VGPR cap (was 128 -> massive scratch spills), k-major weight
// tiles, fast sigmoid/GELU, single pack kernel.

#define CCH   384
#define NPIX  16384
#define BMROWS 64
#define NTHR  512          // 8 waves: 2 (M) x 4 (N)
#define LNEPS 1e-6f

typedef __attribute__((ext_vector_type(8))) short bf8_t;   // 8 x bf16
typedef __attribute__((ext_vector_type(4))) float f4_t;    // 4 x f32
typedef __attribute__((ext_vector_type(8))) unsigned short us8_t;

// workspace offsets (ushort units). Each 16x16x32 B-tile = 512 bf16 = 1KB.
// K-MAJOR tile order: tile = kb * (N/16) + n16   (kb = K/32 block)
#define OFF_WU 0u
#define OFF_WG 147456u      // 288 tiles * 512
#define OFF_A  294912u
#define OFF_W1 442368u      // 384x1536 -> 1152 tiles
#define OFF_W2 1032192u     // 1536x384 -> 1152 tiles
// total 1622016 ushorts = 3.1 MB of d_ws

__device__ __forceinline__ unsigned short f2bf(float f) {
  union { float f; unsigned u; } x; x.f = f;
  unsigned r = (x.u >> 16) & 1u;
  return (unsigned short)((x.u + 0x7fffu + r) >> 16);   // RNE
}
__device__ __forceinline__ float bf2f(unsigned short h) {
  union { unsigned u; float f; } x; x.u = ((unsigned)h) << 16;
  return x.f;
}
__device__ __forceinline__ float fsigmoid(float z) {
  return __builtin_amdgcn_rcpf(1.f + __expf(-z));
}

// Pack all five f32 weights into bf16 MFMA-B fragment order, k-major tiles:
// P[off + tile*512 + lane*8 + j] = W[kb*32 + (lane>>4)*8 + j][n16*16 + (lane&15)]
__global__ void pack_all(const float* __restrict__ Wu, const float* __restrict__ Wg,
                         const float* __restrict__ A,  const float* __restrict__ W1,
                         const float* __restrict__ W2, unsigned short* __restrict__ P) {
  const int gid = blockIdx.x * blockDim.x + threadIdx.x;
  const int l = gid & 63;
  int tile = gid >> 6;
  const float* W; int N; unsigned off; int t;
  if      (tile <  288) { W = Wu; N = 384;  off = OFF_WU; t = tile;        }
  else if (tile <  576) { W = Wg; N = 384;  off = OFF_WG; t = tile - 288;  }
  else if (tile <  864) { W = A;  N = 384;  off = OFF_A;  t = tile - 576;  }
  else if (tile < 2016) { W = W1; N = 1536; off = OFF_W1; t = tile - 864;  }
  else if (tile < 3168) { W = W2; N = 384;  off = OFF_W2; t = tile - 2016; }
  else return;
  const int ntn = N >> 4;
  const int kb  = t / ntn, n16 = t % ntn;
  const int krow = kb * 32 + ((l >> 4) << 3);
  const int col  = n16 * 16 + (l & 15);
  us8_t pk;
  #pragma unroll
  for (int j = 0; j < 8; ++j) pk[j] = f2bf(W[(size_t)(krow + j) * N + col]);
  *reinterpret_cast<us8_t*>(P + off + ((size_t)t << 9) + (l << 3)) = pk;
}

// acc[2][6] += A(LDS rows mw*32..mw*32+31, swizzled) * B(packed k-major tiles)
__device__ __forceinline__ void gemm_acc(const unsigned short* sb,
                                         const unsigned short* __restrict__ bp,
                                         int kb0, int ntn, int n16base,
                                         int mw, int lane, f4_t acc[2][6]) {
  const int ar0 = mw * 32 + (lane & 15);
  const int ar1 = ar0 + 16;
  const int sw  = (ar0 & 7) << 3;        // (ar1&7)==(ar0&7)
  const int koff = (lane >> 4) << 3;
  #pragma unroll
  for (int kb = 0; kb < 12; ++kb) {
    const int ac = kb * 32 + koff;
    const bf8_t a0 = *reinterpret_cast<const bf8_t*>(&sb[ar0 * CCH + (ac ^ sw)]);
    const bf8_t a1 = *reinterpret_cast<const bf8_t*>(&sb[ar1 * CCH + (ac ^ sw)]);
    const unsigned short* bt =
        bp + (((size_t)((kb0 + kb) * ntn + n16base) << 9) + (lane << 3));
    #pragma unroll
    for (int nt = 0; nt < 6; ++nt) {
      const bf8_t b = *reinterpret_cast<const bf8_t*>(bt + (nt << 9));
      acc[0][nt] = __builtin_amdgcn_mfma_f32_16x16x32_bf16(a0, b, acc[0][nt], 0, 0, 0);
      acc[1][nt] = __builtin_amdgcn_mfma_f32_16x16x32_bf16(a1, b, acc[1][nt], 0, 0, 0);
    }
  }
}

// write C/D-layout tile (f32 regs) into swizzled bf16 LDS buffer
__device__ __forceinline__ void write_tile(unsigned short* sb, const f4_t t[2][6],
                                           int mw, int nw, int lane) {
  const int cb = nw * 96 + (lane & 15);
  #pragma unroll
  for (int mt = 0; mt < 2; ++mt)
    #pragma unroll
    for (int j = 0; j < 4; ++j) {
      const int row = mw * 32 + mt * 16 + ((lane >> 4) << 2) + j;
      const int sw = (row & 7) << 3;
      #pragma unroll
      for (int nt = 0; nt < 6; ++nt)
        sb[row * CCH + ((cb + nt * 16) ^ sw)] = f2bf(t[mt][nt][j]);
    }
}

__device__ __forceinline__ void zero_acc(f4_t a[2][6]) {
  #pragma unroll
  for (int mt = 0; mt < 2; ++mt)
    #pragma unroll
    for (int nt = 0; nt < 6; ++nt) a[mt][nt] = (f4_t){0.f, 0.f, 0.f, 0.f};
}

__global__ __launch_bounds__(NTHR, 1) void cssm_main(
    const float* __restrict__ x,
    const float* __restrict__ n1s, const float* __restrict__ n1b,
    const float* __restrict__ bu, const float* __restrict__ bg,
    const float* __restrict__ n2s, const float* __restrict__ n2b,
    const float* __restrict__ b1, const float* __restrict__ b2,
    const unsigned short* __restrict__ wp,
    float* __restrict__ out) {
  __shared__ unsigned short sbuf[BMROWS * CCH];   // 48 KB, xn -> h -> x1/xn2 -> m
  __shared__ float srow[2 * BMROWS];              // LN2 mu, rs

  const int tid = threadIdx.x;
  const int lane = tid & 63;
  const int wv = tid >> 6;
  const int mw = wv >> 2, nw = wv & 3;            // wave tile: 32 rows x 96 cols
  const int r0 = blockIdx.x * BMROWS;

  // ---------------- Phase A: LN1 -> sbuf (bf16, swizzled) ----------------
  {
    const int row = tid >> 3, seg = tid & 7;      // 8 threads / row, 48 elems each
    const float* xr = x + (size_t)(r0 + row) * CCH + seg * 48;
    float v[48];
    float s = 0.f, s2 = 0.f;
    #pragma unroll
    for (int i = 0; i < 12; ++i) {
      const f4_t t = reinterpret_cast<const f4_t*>(xr)[i];
      #pragma unroll
      for (int j = 0; j < 4; ++j) { const float f = t[j]; v[i * 4 + j] = f; s += f; s2 += f * f; }
    }
    #pragma unroll
    for (int o = 1; o < 8; o <<= 1) { s += __shfl_xor(s, o, 64); s2 += __shfl_xor(s2, o, 64); }
    const float mu = s * (1.f / CCH);
    const float rs = rsqrtf(fmaxf(s2 * (1.f / CCH) - mu * mu, 0.f) + LNEPS);
    const int sw = (row & 7) << 3;
    #pragma unroll
    for (int g8 = 0; g8 < 6; ++g8) {
      us8_t pk;
      #pragma unroll
      for (int j = 0; j < 8; ++j) {
        const int colc = seg * 48 + g8 * 8 + j;
        pk[j] = f2bf((v[g8 * 8 + j] - mu) * rs * n1s[colc] + n1b[colc]);
      }
      *reinterpret_cast<us8_t*>(&sbuf[row * CCH + ((seg * 48 + g8 * 8) ^ sw)]) = pk;
    }
  }
  __syncthreads();

  f4_t acc[2][6], g4[2][6], c4[2][6];

  // ---------------- Phase A2: g = sigmoid(xn@Wg + bg), c = (1-g)*(xn@Wu + bu) ----
  zero_acc(acc);
  gemm_acc(sbuf, wp + OFF_WG, 0, 24, nw * 6, mw, lane, acc);
  #pragma unroll
  for (int nt = 0; nt < 6; ++nt) {
    const float bgv = bg[nw * 96 + nt * 16 + (lane & 15)];
    #pragma unroll
    for (int mt = 0; mt < 2; ++mt)
      #pragma unroll
      for (int j = 0; j < 4; ++j)
        g4[mt][nt][j] = fsigmoid(acc[mt][nt][j] + bgv);
  }
  zero_acc(acc);
  gemm_acc(sbuf, wp + OFF_WU, 0, 24, nw * 6, mw, lane, acc);
  #pragma unroll
  for (int nt = 0; nt < 6; ++nt) {
    const float buv = bu[nw * 96 + nt * 16 + (lane & 15)];
    #pragma unroll
    for (int mt = 0; mt < 2; ++mt)
      #pragma unroll
      for (int j = 0; j < 4; ++j)
        c4[mt][nt][j] = (1.f - g4[mt][nt][j]) * (acc[mt][nt][j] + buv);
  }

  // ---------------- Phase B: recurrence h_{t+1} = g * (h_t @ A) + c --------------
  __syncthreads();                 // all waves done reading xn
  write_tile(sbuf, c4, mw, nw, lane);   // h1 = c  (h0 = 0)
  __syncthreads();
  #pragma unroll 1
  for (int stp = 0; stp < 7; ++stp) {   // steps 2..8
    zero_acc(acc);
    gemm_acc(sbuf, wp + OFF_A, 0, 24, nw * 6, mw, lane, acc);
    #pragma unroll
    for (int mt = 0; mt < 2; ++mt)
      #pragma unroll
      for (int nt = 0; nt < 6; ++nt)
        #pragma unroll
        for (int j = 0; j < 4; ++j)
          acc[mt][nt][j] = g4[mt][nt][j] * acc[mt][nt][j] + c4[mt][nt][j];
    __syncthreads();               // reads of h done before overwrite
    if (stp < 6) { write_tile(sbuf, acc, mw, nw, lane); __syncthreads(); }
  }

  // ---------------- Phase C: x1 = x + h; LN2 -> xn2 in sbuf ----------------------
  f4_t x14[2][6];
  #pragma unroll
  for (int mt = 0; mt < 2; ++mt)
    #pragma unroll
    for (int j = 0; j < 4; ++j) {
      const int row = mw * 32 + mt * 16 + ((lane >> 4) << 2) + j;
      #pragma unroll
      for (int nt = 0; nt < 6; ++nt) {
        const int col = nw * 96 + nt * 16 + (lane & 15);
        x14[mt][nt][j] = x[(size_t)(r0 + row) * CCH + col] + acc[mt][nt][j];
      }
    }
  write_tile(sbuf, x14, mw, nw, lane);   // x1 (bf16) for LN2 stats
  __syncthreads();
  {
    const int row = tid >> 3, seg = tid & 7;
    const int sw = (row & 7) << 3;
    float v[48];
    float s = 0.f, s2 = 0.f;
    #pragma unroll
    for (int g8 = 0; g8 < 6; ++g8) {
      const us8_t t = *reinterpret_cast<const us8_t*>(&sbuf[row * CCH + ((seg * 48 + g8 * 8) ^ sw)]);
      #pragma unroll
      for (int j = 0; j < 8; ++j) { const float f = bf2f(t[j]); v[g8 * 8 + j] = f; s += f; s2 += f * f; }
    }
    #pragma unroll
    for (int o = 1; o < 8; o <<= 1) { s += __shfl_xor(s, o, 64); s2 += __shfl_xor(s2, o, 64); }
    const float mu = s * (1.f / CCH);
    const float rs = rsqrtf(fmaxf(s2 * (1.f / CCH) - mu * mu, 0.f) + LNEPS);
    if (seg == 0) { srow[row] = mu; srow[64 + row] = rs; }
    #pragma unroll
    for (int g8 = 0; g8 < 6; ++g8) {
      us8_t pk;
      #pragma unroll
      for (int j = 0; j < 8; ++j) {
        const int colc = seg * 48 + g8 * 8 + j;
        pk[j] = f2bf((v[g8 * 8 + j] - mu) * rs * n2s[colc] + n2b[colc]);
      }
      *reinterpret_cast<us8_t*>(&sbuf[row * CCH + ((seg * 48 + g8 * 8) ^ sw)]) = pk;
    }
  }
  __syncthreads();

  // ---------------- Phase D: MLP in 4 HID-chunks of 384 --------------------------
  float sc2[6], bs2[6];
  #pragma unroll
  for (int nt = 0; nt < 6; ++nt) {
    const int colc = nw * 96 + nt * 16 + (lane & 15);
    sc2[nt] = n2s[colc]; bs2[nt] = n2b[colc];
  }
  f4_t aco[2][6];
  zero_acc(aco);
  #pragma unroll 1
  for (int ch = 0; ch < 4; ++ch) {
    if (ch > 0) {          // regenerate xn2 into sbuf from x1 regs + row stats
      #pragma unroll
      for (int mt = 0; mt < 2; ++mt)
        #pragma unroll
        for (int j = 0; j < 4; ++j) {
          const int row = mw * 32 + mt * 16 + ((lane >> 4) << 2) + j;
          const float mu = srow[row], rs = srow[64 + row];
          const int sw = (row & 7) << 3;
          #pragma unroll
          for (int nt = 0; nt < 6; ++nt) {
            const int col = nw * 96 + nt * 16 + (lane & 15);
            sbuf[row * CCH + (col ^ sw)] = f2bf((x14[mt][nt][j] - mu) * rs * sc2[nt] + bs2[nt]);
          }
        }
      __syncthreads();
    }
    f4_t am[2][6];
    zero_acc(am);
    gemm_acc(sbuf, wp + OFF_W1, 0, 96, ch * 24 + nw * 6, mw, lane, am);
    #pragma unroll
    for (int nt = 0; nt < 6; ++nt) {
      const float b1v = b1[ch * 384 + nw * 96 + nt * 16 + (lane & 15)];
      #pragma unroll
      for (int mt = 0; mt < 2; ++mt)
        #pragma unroll
        for (int j = 0; j < 4; ++j) {
          // gelu(z) = z * sigmoid(2*0.79788456*(z + 0.044715 z^3))  (tanh form)
          const float z = am[mt][nt][j] + b1v;
          const float w = 1.5957691216057308f * (z + 0.044715f * z * z * z);
          am[mt][nt][j] = z * fsigmoid(w);
        }
    }
    __syncthreads();               // all waves done reading xn2
    write_tile(sbuf, am, mw, nw, lane);
    __syncthreads();
    gemm_acc(sbuf, wp + OFF_W2, ch * 12, 24, nw * 6, mw, lane, aco);
    __syncthreads();     // before next chunk overwrites sbuf
  }

  // ---------------- Phase E: out = x1 + mlp + b2 ---------------------------------
  #pragma unroll
  for (int nt = 0; nt < 6; ++nt) {
    const int col = nw * 96 + nt * 16 + (lane & 15);
    const float b2v = b2[col];
    #pragma unroll
    for (int mt = 0; mt < 2; ++mt)
      #pragma unroll
      for (int j = 0; j < 4; ++j) {
        const int row = mw * 32 + mt * 16 + ((lane >> 4) << 2) + j;
        out[(size_t)(r0 + row) * CCH + col] = x14[mt][nt][j] + aco[mt][nt][j] + b2v;
      }
  }
}

extern "C" void kernel_launch(void* const* d_in, const int* in_sizes, int n_in,
                              void* d_out, int out_size, void* d_ws, size_t ws_size,
                              hipStream_t stream) {
  const float* x   = (const float*)d_in[0];
  const float* n1s = (const float*)d_in[1];
  const float* n1b = (const float*)d_in[2];
  const float* Wu  = (const float*)d_in[3];
  const float* bu  = (const float*)d_in[4];
  const float* Wg  = (const float*)d_in[5];
  const float* bg  = (const float*)d_in[6];
  const float* A   = (const float*)d_in[7];
  const float* n2s = (const float*)d_in[8];
  const float* n2b = (const float*)d_in[9];
  const float* W1  = (const float*)d_in[10];
  const float* b1  = (const float*)d_in[11];
  const float* W2  = (const float*)d_in[12];
  const float* b2  = (const float*)d_in[13];
  unsigned short* wp = (unsigned short*)d_ws;
  float* out = (float*)d_out;

  // pack all weights to bf16 fragment order (one launch; 3168 tiles * 64 lanes)
  pack_all<<<(3168 * 64) / 256, 256, 0, stream>>>(Wu, Wg, A, W1, W2, wp);

  cssm_main<<<NPIX / BMROWS, NTHR, 0, stream>>>(
      x, n1s, n1b, bu, bg, n2s, n2b, b1, b2, wp, out);
}

// Round 3
// 332.879 us; speedup vs baseline: 1.7679x; 1.5589x over previous
//
#include <hip/hip_runtime.h>

// CSSM TinyViT block, fused bf16-MFMA implementation for gfx950.
// B=16,H=32,W=32 -> 16384 rows of C=384. T=8, HID=1536.
// Round 3: 1Mx8N wave tiling (64x48 per wave -> no B-frag duplication,
// acc[4][3]=48 regs), amdgpu_waves_per_eu to kill the 128-VGPR spill cap,
// second LDS buffer so xn2 persists (no regen), merged Wu/Wg gemm.

#define CCH   384
#define NPIX  16384
#define BMROWS 64
#define NTHR  512          // 8 waves: 1 (M) x 8 (N); wave tile 64 rows x 48 cols
#define LNEPS 1e-6f

typedef __attribute__((ext_vector_type(8))) short bf8_t;   // 8 x bf16
typedef __attribute__((ext_vector_type(4))) float f4_t;    // 4 x f32
typedef __attribute__((ext_vector_type(8))) unsigned short us8_t;

// workspace offsets (ushort units). Each 16x16x32 B-tile = 512 bf16 = 1KB.
// K-MAJOR tile order: tile = kb * (N/16) + n16   (kb = K/32 block)
#define OFF_WU 0u
#define OFF_WG 147456u      // 288 tiles * 512
#define OFF_A  294912u
#define OFF_W1 442368u      // 384x1536 -> 1152 tiles
#define OFF_W2 1032192u     // 1536x384 -> 1152 tiles

__device__ __forceinline__ unsigned short f2bf(float f) {
  union { float f; unsigned u; } x; x.f = f;
  unsigned r = (x.u >> 16) & 1u;
  return (unsigned short)((x.u + 0x7fffu + r) >> 16);   // RNE
}
__device__ __forceinline__ float bf2f(unsigned short h) {
  union { unsigned u; float f; } x; x.u = ((unsigned)h) << 16;
  return x.f;
}
__device__ __forceinline__ float fsigmoid(float z) {
  return __builtin_amdgcn_rcpf(1.f + __expf(-z));
}

// Pack all five f32 weights into bf16 MFMA-B fragment order, k-major tiles:
// P[off + tile*512 + lane*8 + j] = W[kb*32 + (lane>>4)*8 + j][n16*16 + (lane&15)]
__global__ void pack_all(const float* __restrict__ Wu, const float* __restrict__ Wg,
                         const float* __restrict__ A,  const float* __restrict__ W1,
                         const float* __restrict__ W2, unsigned short* __restrict__ P) {
  const int gid = blockIdx.x * blockDim.x + threadIdx.x;
  const int l = gid & 63;
  int tile = gid >> 6;
  const float* W; int N; unsigned off; int t;
  if      (tile <  288) { W = Wu; N = 384;  off = OFF_WU; t = tile;        }
  else if (tile <  576) { W = Wg; N = 384;  off = OFF_WG; t = tile - 288;  }
  else if (tile <  864) { W = A;  N = 384;  off = OFF_A;  t = tile - 576;  }
  else if (tile < 2016) { W = W1; N = 1536; off = OFF_W1; t = tile - 864;  }
  else if (tile < 3168) { W = W2; N = 384;  off = OFF_W2; t = tile - 2016; }
  else return;
  const int ntn = N >> 4;
  const int kb  = t / ntn, n16 = t % ntn;
  const int krow = kb * 32 + ((l >> 4) << 3);
  const int col  = n16 * 16 + (l & 15);
  us8_t pk;
  #pragma unroll
  for (int j = 0; j < 8; ++j) pk[j] = f2bf(W[(size_t)(krow + j) * N + col]);
  *reinterpret_cast<us8_t*>(P + off + ((size_t)t << 9) + (l << 3)) = pk;
}

// acc[4][3] += A(all 64 LDS rows, swizzled) * B(3 packed k-major tiles)
// nkb k-blocks of 32 starting at kb0; B tiles at n16base..n16base+2.
template <int NKB>
__device__ __forceinline__ void gemm_acc(const unsigned short* sb,
                                         const unsigned short* __restrict__ bp,
                                         int kb0, int ntn, int n16base,
                                         int lane, f4_t acc[4][3]) {
  const int r    = lane & 15;
  const int sw   = (lane & 7) << 3;
  const int koff = (lane >> 4) << 3;
  #pragma unroll
  for (int kb = 0; kb < NKB; ++kb) {
    const int ac = (kb * 32 + koff) ^ sw;
    bf8_t a[4];
    #pragma unroll
    for (int mt = 0; mt < 4; ++mt)
      a[mt] = *reinterpret_cast<const bf8_t*>(&sb[(mt * 16 + r) * CCH + ac]);
    const unsigned short* bt =
        bp + (((size_t)((kb0 + kb) * ntn + n16base) << 9) + (lane << 3));
    #pragma unroll
    for (int nt = 0; nt < 3; ++nt) {
      const bf8_t b = *reinterpret_cast<const bf8_t*>(bt + (nt << 9));
      #pragma unroll
      for (int mt = 0; mt < 4; ++mt)
        acc[mt][nt] = __builtin_amdgcn_mfma_f32_16x16x32_bf16(a[mt], b, acc[mt][nt], 0, 0, 0);
    }
  }
}

// Merged two-GEMM version (shared A-fragment reads): Wg -> accG, Wu -> accU.
__device__ __forceinline__ void gemm_acc2(const unsigned short* sb,
                                          const unsigned short* __restrict__ bpG,
                                          const unsigned short* __restrict__ bpU,
                                          int n16base, int lane,
                                          f4_t accG[4][3], f4_t accU[4][3]) {
  const int r    = lane & 15;
  const int sw   = (lane & 7) << 3;
  const int koff = (lane >> 4) << 3;
  #pragma unroll
  for (int kb = 0; kb < 12; ++kb) {
    const int ac = (kb * 32 + koff) ^ sw;
    bf8_t a[4];
    #pragma unroll
    for (int mt = 0; mt < 4; ++mt)
      a[mt] = *reinterpret_cast<const bf8_t*>(&sb[(mt * 16 + r) * CCH + ac]);
    const size_t toff = (((size_t)(kb * 24 + n16base)) << 9) + (lane << 3);
    #pragma unroll
    for (int nt = 0; nt < 3; ++nt) {
      const bf8_t bG = *reinterpret_cast<const bf8_t*>(bpG + toff + (nt << 9));
      const bf8_t bU = *reinterpret_cast<const bf8_t*>(bpU + toff + (nt << 9));
      #pragma unroll
      for (int mt = 0; mt < 4; ++mt) {
        accG[mt][nt] = __builtin_amdgcn_mfma_f32_16x16x32_bf16(a[mt], bG, accG[mt][nt], 0, 0, 0);
        accU[mt][nt] = __builtin_amdgcn_mfma_f32_16x16x32_bf16(a[mt], bU, accU[mt][nt], 0, 0, 0);
      }
    }
  }
}

// write C/D-layout wave tile (64 x 48, f32 regs) into swizzled bf16 LDS buffer
__device__ __forceinline__ void write_tile(unsigned short* sb, const f4_t t[4][3],
                                           int nw, int lane) {
  const int cb = nw * 48 + (lane & 15);
  #pragma unroll
  for (int mt = 0; mt < 4; ++mt)
    #pragma unroll
    for (int j = 0; j < 4; ++j) {
      const int row = mt * 16 + ((lane >> 4) << 2) + j;
      const int sw = (row & 7) << 3;
      #pragma unroll
      for (int nt = 0; nt < 3; ++nt)
        sb[row * CCH + ((cb + nt * 16) ^ sw)] = f2bf(t[mt][nt][j]);
    }
}

__device__ __forceinline__ void zero_acc(f4_t a[4][3]) {
  #pragma unroll
  for (int mt = 0; mt < 4; ++mt)
    #pragma unroll
    for (int nt = 0; nt < 3; ++nt) a[mt][nt] = (f4_t){0.f, 0.f, 0.f, 0.f};
}

// LN helper: 8 threads per row, 48 elems each, stats over 384
__device__ __forceinline__ void ln_rw(const unsigned short* src, unsigned short* dst,
                                      const float* __restrict__ scale,
                                      const float* __restrict__ bias, int tid) {
  const int row = tid >> 3, seg = tid & 7;
  const int sw = (row & 7) << 3;
  float v[48];
  float s = 0.f, s2 = 0.f;
  #pragma unroll
  for (int g8 = 0; g8 < 6; ++g8) {
    const us8_t t = *reinterpret_cast<const us8_t*>(&src[row * CCH + ((seg * 48 + g8 * 8) ^ sw)]);
    #pragma unroll
    for (int j = 0; j < 8; ++j) { const float f = bf2f(t[j]); v[g8 * 8 + j] = f; s += f; s2 += f * f; }
  }
  #pragma unroll
  for (int o = 1; o < 8; o <<= 1) { s += __shfl_xor(s, o, 64); s2 += __shfl_xor(s2, o, 64); }
  const float mu = s * (1.f / CCH);
  const float rs = rsqrtf(fmaxf(s2 * (1.f / CCH) - mu * mu, 0.f) + LNEPS);
  #pragma unroll
  for (int g8 = 0; g8 < 6; ++g8) {
    us8_t pk;
    #pragma unroll
    for (int j = 0; j < 8; ++j) {
      const int colc = seg * 48 + g8 * 8 + j;
      pk[j] = f2bf((v[g8 * 8 + j] - mu) * rs * scale[colc] + bias[colc]);
    }
    *reinterpret_cast<us8_t*>(&dst[row * CCH + ((seg * 48 + g8 * 8) ^ sw)]) = pk;
  }
}

__global__ __launch_bounds__(NTHR)
__attribute__((amdgpu_waves_per_eu(1, 2)))
void cssm_main(
    const float* __restrict__ x,
    const float* __restrict__ n1s, const float* __restrict__ n1b,
    const float* __restrict__ bu, const float* __restrict__ bg,
    const float* __restrict__ n2s, const float* __restrict__ n2b,
    const float* __restrict__ b1, const float* __restrict__ b2,
    const unsigned short* __restrict__ wp,
    float* __restrict__ out) {
  __shared__ unsigned short sbuf[BMROWS * CCH];   // 48 KB: xn -> h -> xn2 (persists)
  __shared__ unsigned short mbuf[BMROWS * CCH];   // 48 KB: x1 stats staging -> m

  const int tid = threadIdx.x;
  const int lane = tid & 63;
  const int nw = tid >> 6;                         // wave n-slot: cols nw*48..+47
  const int r0 = blockIdx.x * BMROWS;

  // ---------------- Phase A: LN1(x) -> sbuf (bf16, swizzled) ----------------
  {
    const int row = tid >> 3, seg = tid & 7;
    const float* xr = x + (size_t)(r0 + row) * CCH + seg * 48;
    float v[48];
    float s = 0.f, s2 = 0.f;
    #pragma unroll
    for (int i = 0; i < 12; ++i) {
      const f4_t t = reinterpret_cast<const f4_t*>(xr)[i];
      #pragma unroll
      for (int j = 0; j < 4; ++j) { const float f = t[j]; v[i * 4 + j] = f; s += f; s2 += f * f; }
    }
    #pragma unroll
    for (int o = 1; o < 8; o <<= 1) { s += __shfl_xor(s, o, 64); s2 += __shfl_xor(s2, o, 64); }
    const float mu = s * (1.f / CCH);
    const float rs = rsqrtf(fmaxf(s2 * (1.f / CCH) - mu * mu, 0.f) + LNEPS);
    const int sw = (row & 7) << 3;
    #pragma unroll
    for (int g8 = 0; g8 < 6; ++g8) {
      us8_t pk;
      #pragma unroll
      for (int j = 0; j < 8; ++j) {
        const int colc = seg * 48 + g8 * 8 + j;
        pk[j] = f2bf((v[g8 * 8 + j] - mu) * rs * n1s[colc] + n1b[colc]);
      }
      *reinterpret_cast<us8_t*>(&sbuf[row * CCH + ((seg * 48 + g8 * 8) ^ sw)]) = pk;
    }
  }
  __syncthreads();

  // ---------------- Phase A2: merged  g = sigm(xn@Wg+bg), c = (1-g)(xn@Wu+bu) ----
  f4_t g4[4][3], c4[4][3];
  zero_acc(g4); zero_acc(c4);
  gemm_acc2(sbuf, wp + OFF_WG, wp + OFF_WU, nw * 3, lane, g4, c4);
  #pragma unroll
  for (int nt = 0; nt < 3; ++nt) {
    const int col = nw * 48 + nt * 16 + (lane & 15);
    const float bgv = bg[col], buv = bu[col];
    #pragma unroll
    for (int mt = 0; mt < 4; ++mt)
      #pragma unroll
      for (int j = 0; j < 4; ++j) {
        const float g = fsigmoid(g4[mt][nt][j] + bgv);
        g4[mt][nt][j] = g;
        c4[mt][nt][j] = (1.f - g) * (c4[mt][nt][j] + buv);
      }
  }

  // ---------------- Phase B: recurrence h' = g*(h@A) + c  (h1 = c) ---------------
  __syncthreads();                       // all waves done reading xn from sbuf
  write_tile(sbuf, c4, nw, lane);        // h1 = c
  __syncthreads();
  f4_t acc[4][3];
  #pragma unroll 1
  for (int stp = 0; stp < 7; ++stp) {    // steps 2..8
    zero_acc(acc);
    gemm_acc<12>(sbuf, wp + OFF_A, 0, 24, nw * 3, lane, acc);
    #pragma unroll
    for (int mt = 0; mt < 4; ++mt)
      #pragma unroll
      for (int nt = 0; nt < 3; ++nt)
        #pragma unroll
        for (int j = 0; j < 4; ++j)
          acc[mt][nt][j] = g4[mt][nt][j] * acc[mt][nt][j] + c4[mt][nt][j];
    __syncthreads();                     // reads of h done before overwrite
    if (stp < 6) { write_tile(sbuf, acc, nw, lane); __syncthreads(); }
  }

  // ---------------- Phase C: x1 = x + h (f32 regs); LN2 -> xn2 in sbuf -----------
  f4_t x14[4][3];
  #pragma unroll
  for (int mt = 0; mt < 4; ++mt)
    #pragma unroll
    for (int j = 0; j < 4; ++j) {
      const int row = mt * 16 + ((lane >> 4) << 2) + j;
      #pragma unroll
      for (int nt = 0; nt < 3; ++nt) {
        const int col = nw * 48 + nt * 16 + (lane & 15);
        x14[mt][nt][j] = x[(size_t)(r0 + row) * CCH + col] + acc[mt][nt][j];
      }
    }
  write_tile(mbuf, x14, nw, lane);       // x1 (bf16) for LN2 stats
  __syncthreads();
  ln_rw(mbuf, sbuf, n2s, n2b, tid);      // xn2 -> sbuf (persists through MLP)
  __syncthreads();

  // ---------------- Phase D: MLP in 4 HID-chunks of 384 --------------------------
  f4_t aco[4][3];
  zero_acc(aco);
  #pragma unroll 1
  for (int ch = 0; ch < 4; ++ch) {
    f4_t am[4][3];
    zero_acc(am);
    gemm_acc<12>(sbuf, wp + OFF_W1, 0, 96, ch * 24 + nw * 3, lane, am);
    #pragma unroll
    for (int nt = 0; nt < 3; ++nt) {
      const float b1v = b1[ch * 384 + nw * 48 + nt * 16 + (lane & 15)];
      #pragma unroll
      for (int mt = 0; mt < 4; ++mt)
        #pragma unroll
        for (int j = 0; j < 4; ++j) {
          // gelu(z) = z * sigmoid(1.595769122*(z + 0.044715 z^3))  (tanh form)
          const float z = am[mt][nt][j] + b1v;
          const float w = 1.5957691216057308f * (z + 0.044715f * z * z * z);
          am[mt][nt][j] = z * fsigmoid(w);
        }
    }
    __syncthreads();                     // prev readers of mbuf done
    write_tile(mbuf, am, nw, lane);
    __syncthreads();
    gemm_acc<12>(mbuf, wp + OFF_W2, ch * 12, 24, nw * 3, lane, aco);
  }

  // ---------------- Phase E: out = x1 + mlp + b2 ---------------------------------
  #pragma unroll
  for (int nt = 0; nt < 3; ++nt) {
    const int col = nw * 48 + nt * 16 + (lane & 15);
    const float b2v = b2[col];
    #pragma unroll
    for (int mt = 0; mt < 4; ++mt)
      #pragma unroll
      for (int j = 0; j < 4; ++j) {
        const int row = mt * 16 + ((lane >> 4) << 2) + j;
        out[(size_t)(r0 + row) * CCH + col] = x14[mt][nt][j] + aco[mt][nt][j] + b2v;
      }
  }
}

extern "C" void kernel_launch(void* const* d_in, const int* in_sizes, int n_in,
                              void* d_out, int out_size, void* d_ws, size_t ws_size,
                              hipStream_t stream) {
  const float* x   = (const float*)d_in[0];
  const float* n1s = (const float*)d_in[1];
  const float* n1b = (const float*)d_in[2];
  const float* Wu  = (const float*)d_in[3];
  const float* bu  = (const float*)d_in[4];
  const float* Wg  = (const float*)d_in[5];
  const float* bg  = (const float*)d_in[6];
  const float* A   = (const float*)d_in[7];
  const float* n2s = (const float*)d_in[8];
  const float* n2b = (const float*)d_in[9];
  const float* W1  = (const float*)d_in[10];
  const float* b1  = (const float*)d_in[11];
  const float* W2  = (const float*)d_in[12];
  const float* b2  = (const float*)d_in[13];
  unsigned short* wp = (unsigned short*)d_ws;
  float* out = (float*)d_out;

  // pack all weights to bf16 fragment order (one launch; 3168 tiles * 64 lanes)
  pack_all<<<(3168 * 64) / 256, 256, 0, stream>>>(Wu, Wg, A, W1, W2, wp);

  cssm_main<<<NPIX / BMROWS, NTHR, 0, stream>>>(
      x, n1s, n1b, bu, bg, n2s, n2b, b1, b2, wp, out);
}

// Round 4
// 163.242 us; speedup vs baseline: 3.6051x; 2.0392x over previous
//
#include <hip/hip_runtime.h>

// CSSM TinyViT block, fused bf16-MFMA implementation for gfx950.
// B=16,H=32,W=32 -> 16384 rows of C=384. T=8, HID=1536.
// Round 4: kill register spills by capping the live set. g/c live in LDS
// (bf16, per-thread-contiguous runs, streamed 8-at-a-time); h8 lives in LDS;
// final residual re-reads x. Peak live regs ~= one 48-f32 acc + temps.
// LDS: sbuf(48K: xn->h->xn2) + gbuf(48K: g->h8) + cbuf(48K: c->m) = 144KB.

#define CCH   384
#define NPIX  16384
#define BMROWS 64
#define NTHR  512          // 8 waves: 1 (M) x 8 (N); wave tile 64 rows x 48 cols
#define LNEPS 1e-6f

typedef __attribute__((ext_vector_type(8))) short bf8_t;   // 8 x bf16
typedef __attribute__((ext_vector_type(4))) float f4_t;    // 4 x f32
typedef __attribute__((ext_vector_type(8))) unsigned short us8_t;

// workspace offsets (ushort units). Each 16x16x32 B-tile = 512 bf16 = 1KB.
// K-MAJOR tile order: tile = kb * (N/16) + n16   (kb = K/32 block)
#define OFF_WU 0u
#define OFF_WG 147456u      // 288 tiles * 512
#define OFF_A  294912u
#define OFF_W1 442368u      // 384x1536 -> 1152 tiles
#define OFF_W2 1032192u     // 1536x384 -> 1152 tiles

__device__ __forceinline__ unsigned short f2bf(float f) {
  union { float f; unsigned u; } x; x.f = f;
  unsigned r = (x.u >> 16) & 1u;
  return (unsigned short)((x.u + 0x7fffu + r) >> 16);   // RNE
}
__device__ __forceinline__ float bf2f(unsigned short h) {
  union { unsigned u; float f; } x; x.u = ((unsigned)h) << 16;
  return x.f;
}
__device__ __forceinline__ float fsigmoid(float z) {
  return __builtin_amdgcn_rcpf(1.f + __expf(-z));
}

// Pack all five f32 weights into bf16 MFMA-B fragment order, k-major tiles:
// P[off + tile*512 + lane*8 + j] = W[kb*32 + (lane>>4)*8 + j][n16*16 + (lane&15)]
__global__ void pack_all(const float* __restrict__ Wu, const float* __restrict__ Wg,
                         const float* __restrict__ A,  const float* __restrict__ W1,
                         const float* __restrict__ W2, unsigned short* __restrict__ P) {
  const int gid = blockIdx.x * blockDim.x + threadIdx.x;
  const int l = gid & 63;
  int tile = gid >> 6;
  const float* W; int N; unsigned off; int t;
  if      (tile <  288) { W = Wu; N = 384;  off = OFF_WU; t = tile;        }
  else if (tile <  576) { W = Wg; N = 384;  off = OFF_WG; t = tile - 288;  }
  else if (tile <  864) { W = A;  N = 384;  off = OFF_A;  t = tile - 576;  }
  else if (tile < 2016) { W = W1; N = 1536; off = OFF_W1; t = tile - 864;  }
  else if (tile < 3168) { W = W2; N = 384;  off = OFF_W2; t = tile - 2016; }
  else return;
  const int ntn = N >> 4;
  const int kb  = t / ntn, n16 = t % ntn;
  const int krow = kb * 32 + ((l >> 4) << 3);
  const int col  = n16 * 16 + (l & 15);
  us8_t pk;
  #pragma unroll
  for (int j = 0; j < 8; ++j) pk[j] = f2bf(W[(size_t)(krow + j) * N + col]);
  *reinterpret_cast<us8_t*>(P + off + ((size_t)t << 9) + (l << 3)) = pk;
}

// acc[4][3] += A(all 64 LDS rows, swizzled) * B(3 packed k-major tiles)
template <int NKB>
__device__ __forceinline__ void gemm_acc(const unsigned short* sb,
                                         const unsigned short* __restrict__ bp,
                                         int kb0, int ntn, int n16base,
                                         int lane, f4_t acc[4][3]) {
  const int r    = lane & 15;
  const int sw   = (lane & 7) << 3;
  const int koff = (lane >> 4) << 3;
  #pragma unroll
  for (int kb = 0; kb < NKB; ++kb) {
    const int ac = (kb * 32 + koff) ^ sw;
    bf8_t a[4];
    #pragma unroll
    for (int mt = 0; mt < 4; ++mt)
      a[mt] = *reinterpret_cast<const bf8_t*>(&sb[(mt * 16 + r) * CCH + ac]);
    const unsigned short* bt =
        bp + (((size_t)((kb0 + kb) * ntn + n16base) << 9) + (lane << 3));
    #pragma unroll
    for (int nt = 0; nt < 3; ++nt) {
      const bf8_t b = *reinterpret_cast<const bf8_t*>(bt + (nt << 9));
      #pragma unroll
      for (int mt = 0; mt < 4; ++mt)
        acc[mt][nt] = __builtin_amdgcn_mfma_f32_16x16x32_bf16(a[mt], b, acc[mt][nt], 0, 0, 0);
    }
  }
}

// Merged two-GEMM version (shared A-fragment reads): Wg -> accG, Wu -> accU.
__device__ __forceinline__ void gemm_acc2(const unsigned short* sb,
                                          const unsigned short* __restrict__ bpG,
                                          const unsigned short* __restrict__ bpU,
                                          int n16base, int lane,
                                          f4_t accG[4][3], f4_t accU[4][3]) {
  const int r    = lane & 15;
  const int sw   = (lane & 7) << 3;
  const int koff = (lane >> 4) << 3;
  #pragma unroll
  for (int kb = 0; kb < 12; ++kb) {
    const int ac = (kb * 32 + koff) ^ sw;
    bf8_t a[4];
    #pragma unroll
    for (int mt = 0; mt < 4; ++mt)
      a[mt] = *reinterpret_cast<const bf8_t*>(&sb[(mt * 16 + r) * CCH + ac]);
    const size_t toff = (((size_t)(kb * 24 + n16base)) << 9) + (lane << 3);
    #pragma unroll
    for (int nt = 0; nt < 3; ++nt) {
      const bf8_t bG = *reinterpret_cast<const bf8_t*>(bpG + toff + (nt << 9));
      const bf8_t bU = *reinterpret_cast<const bf8_t*>(bpU + toff + (nt << 9));
      #pragma unroll
      for (int mt = 0; mt < 4; ++mt) {
        accG[mt][nt] = __builtin_amdgcn_mfma_f32_16x16x32_bf16(a[mt], bG, accG[mt][nt], 0, 0, 0);
        accU[mt][nt] = __builtin_amdgcn_mfma_f32_16x16x32_bf16(a[mt], bU, accU[mt][nt], 0, 0, 0);
      }
    }
  }
}

// write C/D-layout wave tile (64 x 48, f32 regs) into swizzled bf16 LDS tile
__device__ __forceinline__ void write_tile(unsigned short* sb, const f4_t t[4][3],
                                           int nw, int lane) {
  const int cb = nw * 48 + (lane & 15);
  #pragma unroll
  for (int mt = 0; mt < 4; ++mt)
    #pragma unroll
    for (int j = 0; j < 4; ++j) {
      const int row = mt * 16 + ((lane >> 4) << 2) + j;
      const int sw = (row & 7) << 3;
      #pragma unroll
      for (int nt = 0; nt < 3; ++nt)
        sb[row * CCH + ((cb + nt * 16) ^ sw)] = f2bf(t[mt][nt][j]);
    }
}

// per-thread-contiguous bf16 run store/load: layout [6 blocks][512 tid][8 bf16]
__device__ __forceinline__ void store_run(unsigned short* buf, const f4_t t[4][3],
                                          int tid) {
  #pragma unroll
  for (int b = 0; b < 6; ++b) {
    us8_t pk;
    #pragma unroll
    for (int m = 0; m < 8; ++m) {
      const int k = b * 8 + m;
      pk[m] = f2bf(t[k / 12][(k % 12) >> 2][k & 3]);
    }
    *reinterpret_cast<us8_t*>(&buf[b * 4096 + tid * 8]) = pk;
  }
}

// acc = g * acc + c, streaming g/c from LDS runs 8 values at a time
__device__ __forceinline__ void fma_run(f4_t acc[4][3], const unsigned short* gb,
                                        const unsigned short* cb, int tid) {
  #pragma unroll
  for (int b = 0; b < 6; ++b) {
    const us8_t gv = *reinterpret_cast<const us8_t*>(&gb[b * 4096 + tid * 8]);
    const us8_t cv = *reinterpret_cast<const us8_t*>(&cb[b * 4096 + tid * 8]);
    #pragma unroll
    for (int m = 0; m < 8; ++m) {
      const int k = b * 8 + m;
      acc[k / 12][(k % 12) >> 2][k & 3] =
          bf2f(gv[m]) * acc[k / 12][(k % 12) >> 2][k & 3] + bf2f(cv[m]);
    }
  }
}

__device__ __forceinline__ void zero_acc(f4_t a[4][3]) {
  #pragma unroll
  for (int mt = 0; mt < 4; ++mt)
    #pragma unroll
    for (int nt = 0; nt < 3; ++nt) a[mt][nt] = (f4_t){0.f, 0.f, 0.f, 0.f};
}

__global__ __launch_bounds__(NTHR) void cssm_main(
    const float* __restrict__ x,
    const float* __restrict__ n1s, const float* __restrict__ n1b,
    const float* __restrict__ bu, const float* __restrict__ bg,
    const float* __restrict__ n2s, const float* __restrict__ n2b,
    const float* __restrict__ b1, const float* __restrict__ b2,
    const unsigned short* __restrict__ wp,
    float* __restrict__ out) {
  __shared__ unsigned short sbuf[BMROWS * CCH];   // xn -> h(1..7) -> xn2
  __shared__ unsigned short gbuf[BMROWS * CCH];   // g runs -> h8 tile
  __shared__ unsigned short cbuf[BMROWS * CCH];   // c runs -> m tile

  const int tid = threadIdx.x;
  const int lane = tid & 63;
  const int nw = tid >> 6;                         // wave n-slot: cols nw*48..+47
  const int r0 = blockIdx.x * BMROWS;

  // ---------------- Phase A: LN1(x) -> sbuf (bf16, swizzled) ----------------
  {
    const int row = tid >> 3, seg = tid & 7;
    const float* xr = x + (size_t)(r0 + row) * CCH + seg * 48;
    float v[48];
    float s = 0.f, s2 = 0.f;
    #pragma unroll
    for (int i = 0; i < 12; ++i) {
      const f4_t t = reinterpret_cast<const f4_t*>(xr)[i];
      #pragma unroll
      for (int j = 0; j < 4; ++j) { const float f = t[j]; v[i * 4 + j] = f; s += f; s2 += f * f; }
    }
    #pragma unroll
    for (int o = 1; o < 8; o <<= 1) { s += __shfl_xor(s, o, 64); s2 += __shfl_xor(s2, o, 64); }
    const float mu = s * (1.f / CCH);
    const float rs = rsqrtf(fmaxf(s2 * (1.f / CCH) - mu * mu, 0.f) + LNEPS);
    const int sw = (row & 7) << 3;
    #pragma unroll
    for (int g8 = 0; g8 < 6; ++g8) {
      us8_t pk;
      #pragma unroll
      for (int j = 0; j < 8; ++j) {
        const int colc = seg * 48 + g8 * 8 + j;
        pk[j] = f2bf((v[g8 * 8 + j] - mu) * rs * n1s[colc] + n1b[colc]);
      }
      *reinterpret_cast<us8_t*>(&sbuf[row * CCH + ((seg * 48 + g8 * 8) ^ sw)]) = pk;
    }
  }
  __syncthreads();

  // ---------------- Phase A2: g = sigm(xn@Wg+bg), c = (1-g)(xn@Wu+bu) -> LDS runs
  {
    f4_t g4[4][3], c4[4][3];
    zero_acc(g4); zero_acc(c4);
    gemm_acc2(sbuf, wp + OFF_WG, wp + OFF_WU, nw * 3, lane, g4, c4);
    #pragma unroll
    for (int nt = 0; nt < 3; ++nt) {
      const int col = nw * 48 + nt * 16 + (lane & 15);
      const float bgv = bg[col], buv = bu[col];
      #pragma unroll
      for (int mt = 0; mt < 4; ++mt)
        #pragma unroll
        for (int j = 0; j < 4; ++j) {
          const float g = fsigmoid(g4[mt][nt][j] + bgv);
          g4[mt][nt][j] = g;
          c4[mt][nt][j] = (1.f - g) * (c4[mt][nt][j] + buv);
        }
    }
    store_run(gbuf, g4, tid);
    store_run(cbuf, c4, tid);
    __syncthreads();                   // all waves done reading xn from sbuf
    write_tile(sbuf, c4, nw, lane);    // h1 = c
  }
  __syncthreads();

  // ---------------- Phase B: recurrence h' = g*(h@A) + c  (7 steps) --------------
  f4_t acc[4][3];
  #pragma unroll 1
  for (int stp = 0; stp < 7; ++stp) {    // h2..h8
    zero_acc(acc);
    gemm_acc<12>(sbuf, wp + OFF_A, 0, 24, nw * 3, lane, acc);
    fma_run(acc, gbuf, cbuf, tid);       // acc = g*acc + c (own values, no barrier)
    __syncthreads();                     // reads of h done before overwrite
    if (stp < 6) { write_tile(sbuf, acc, nw, lane); __syncthreads(); }
  }

  // ---------------- Phase C: h8 -> gbuf; LN2(x + h8) -> xn2 in sbuf --------------
  write_tile(gbuf, acc, nw, lane);       // h8 (bf16 tile; persists to Phase E)
  __syncthreads();
  {
    const int row = tid >> 3, seg = tid & 7;
    const int sw = (row & 7) << 3;
    const float* xr = x + (size_t)(r0 + row) * CCH + seg * 48;
    float v[48];
    float s = 0.f, s2 = 0.f;
    #pragma unroll
    for (int g8 = 0; g8 < 6; ++g8) {
      const us8_t hv = *reinterpret_cast<const us8_t*>(&gbuf[row * CCH + ((seg * 48 + g8 * 8) ^ sw)]);
      const f4_t xa = reinterpret_cast<const f4_t*>(xr)[g8 * 2];
      const f4_t xb = reinterpret_cast<const f4_t*>(xr)[g8 * 2 + 1];
      #pragma unroll
      for (int j = 0; j < 4; ++j) {
        const float f0 = xa[j] + bf2f(hv[j]);     v[g8 * 8 + j]     = f0; s += f0; s2 += f0 * f0;
        const float f1 = xb[j] + bf2f(hv[4 + j]); v[g8 * 8 + 4 + j] = f1; s += f1; s2 += f1 * f1;
      }
    }
    #pragma unroll
    for (int o = 1; o < 8; o <<= 1) { s += __shfl_xor(s, o, 64); s2 += __shfl_xor(s2, o, 64); }
    const float mu = s * (1.f / CCH);
    const float rs = rsqrtf(fmaxf(s2 * (1.f / CCH) - mu * mu, 0.f) + LNEPS);
    #pragma unroll
    for (int g8 = 0; g8 < 6; ++g8) {
      us8_t pk;
      #pragma unroll
      for (int j = 0; j < 8; ++j) {
        const int colc = seg * 48 + g8 * 8 + j;
        pk[j] = f2bf((v[g8 * 8 + j] - mu) * rs * n2s[colc] + n2b[colc]);
      }
      *reinterpret_cast<us8_t*>(&sbuf[row * CCH + ((seg * 48 + g8 * 8) ^ sw)]) = pk;
    }
  }
  __syncthreads();

  // ---------------- Phase D: MLP in 4 HID-chunks of 384 --------------------------
  f4_t aco[4][3];
  zero_acc(aco);
  #pragma unroll 1
  for (int ch = 0; ch < 4; ++ch) {
    f4_t am[4][3];
    zero_acc(am);
    gemm_acc<12>(sbuf, wp + OFF_W1, 0, 96, ch * 24 + nw * 3, lane, am);
    #pragma unroll
    for (int nt = 0; nt < 3; ++nt) {
      const float b1v = b1[ch * 384 + nw * 48 + nt * 16 + (lane & 15)];
      #pragma unroll
      for (int mt = 0; mt < 4; ++mt)
        #pragma unroll
        for (int j = 0; j < 4; ++j) {
          // gelu(z) = z * sigmoid(1.595769122*(z + 0.044715 z^3))  (tanh form)
          const float z = am[mt][nt][j] + b1v;
          const float w = 1.5957691216057308f * (z + 0.044715f * z * z * z);
          am[mt][nt][j] = z * fsigmoid(w);
        }
    }
    __syncthreads();                     // prev W2-gemm readers of cbuf done
    write_tile(cbuf, am, nw, lane);
    __syncthreads();
    gemm_acc<12>(cbuf, wp + OFF_W2, ch * 12, 24, nw * 3, lane, aco);
  }

  // ---------------- Phase E: out = x + h8 + mlp + b2 -----------------------------
  #pragma unroll
  for (int nt = 0; nt < 3; ++nt) {
    const int col = nw * 48 + nt * 16 + (lane & 15);
    const float b2v = b2[col];
    #pragma unroll
    for (int mt = 0; mt < 4; ++mt)
      #pragma unroll
      for (int j = 0; j < 4; ++j) {
        const int row = mt * 16 + ((lane >> 4) << 2) + j;
        const float hv = bf2f(gbuf[row * CCH + (col ^ ((row & 7) << 3))]);
        out[(size_t)(r0 + row) * CCH + col] =
            x[(size_t)(r0 + row) * CCH + col] + hv + aco[mt][nt][j] + b2v;
      }
  }
}

extern "C" void kernel_launch(void* const* d_in, const int* in_sizes, int n_in,
                              void* d_out, int out_size, void* d_ws, size_t ws_size,
                              hipStream_t stream) {
  const float* x   = (const float*)d_in[0];
  const float* n1s = (const float*)d_in[1];
  const float* n1b = (const float*)d_in[2];
  const float* Wu  = (const float*)d_in[3];
  const float* bu  = (const float*)d_in[4];
  const float* Wg  = (const float*)d_in[5];
  const float* bg  = (const float*)d_in[6];
  const float* A   = (const float*)d_in[7];
  const float* n2s = (const float*)d_in[8];
  const float* n2b = (const float*)d_in[9];
  const float* W1  = (const float*)d_in[10];
  const float* b1  = (const float*)d_in[11];
  const float* W2  = (const float*)d_in[12];
  const float* b2  = (const float*)d_in[13];
  unsigned short* wp = (unsigned short*)d_ws;
  float* out = (float*)d_out;

  // pack all weights to bf16 fragment order (one launch; 3168 tiles * 64 lanes)
  pack_all<<<(3168 * 64) / 256, 256, 0, stream>>>(Wu, Wg, A, W1, W2, wp);

  cssm_main<<<NPIX / BMROWS, NTHR, 0, stream>>>(
      x, n1s, n1b, bu, bg, n2s, n2b, b1, b2, wp, out);
}

// Round 5
// 150.920 us; speedup vs baseline: 3.8994x; 1.0816x over previous
//
#include <hip/hip_runtime.h>
#include <hip/hip_bf16.h>

// CSSM TinyViT block, fused bf16-MFMA implementation for gfx950.
// B=16,H=32,W=32 -> 16384 rows of C=384. T=8, HID=1536.
// Round 5: native bf16 cvt (HW RNE), g/c in packed-bf16 registers (no LDS
// runs), sequential Wg/Wu gemms, bounded unroll (#pragma unroll 4) to stop
// B-load hoisting spills, double-buffered h (1 barrier/step), h8 in bufC.
// LDS: bA(48K) bB(48K) bC(48K) = 144KB.

#define CCH   384
#define NPIX  16384
#define BMROWS 64
#define NTHR  512          // 8 waves: 1 (M) x 8 (N); wave tile 64 rows x 48 cols
#define LNEPS 1e-6f
#define HBUF  24576        // ushorts per 48KB buffer

typedef __attribute__((ext_vector_type(8))) short bf8_t;   // 8 x bf16
typedef __attribute__((ext_vector_type(4))) float f4_t;    // 4 x f32
typedef __attribute__((ext_vector_type(8))) unsigned short us8_t;

// workspace offsets (ushort units). Each 16x16x32 B-tile = 512 bf16 = 1KB.
// K-MAJOR tile order: tile = kb * (N/16) + n16   (kb = K/32 block)
#define OFF_WU 0u
#define OFF_WG 147456u      // 288 tiles * 512
#define OFF_A  294912u
#define OFF_W1 442368u      // 384x1536 -> 1152 tiles
#define OFF_W2 1032192u     // 1536x384 -> 1152 tiles

__device__ __forceinline__ unsigned short f2bf(float f) {
  return __builtin_bit_cast(unsigned short, __float2bfloat16(f));  // HW RNE cvt
}
__device__ __forceinline__ float bf2f(unsigned short h) {
  union { unsigned u; float f; } x; x.u = ((unsigned)h) << 16;
  return x.f;
}
__device__ __forceinline__ unsigned pack2(float lo, float hi) {
  return (unsigned)f2bf(lo) | ((unsigned)f2bf(hi) << 16);
}
__device__ __forceinline__ float ulo(unsigned u) {
  union { unsigned x; float f; } v; v.x = u << 16; return v.f;
}
__device__ __forceinline__ float uhi(unsigned u) {
  union { unsigned x; float f; } v; v.x = u & 0xffff0000u; return v.f;
}
__device__ __forceinline__ float fsigmoid(float z) {
  return __builtin_amdgcn_rcpf(1.f + __expf(-z));
}

// Pack all five f32 weights into bf16 MFMA-B fragment order, k-major tiles:
// P[off + tile*512 + lane*8 + j] = W[kb*32 + (lane>>4)*8 + j][n16*16 + (lane&15)]
__global__ void pack_all(const float* __restrict__ Wu, const float* __restrict__ Wg,
                         const float* __restrict__ A,  const float* __restrict__ W1,
                         const float* __restrict__ W2, unsigned short* __restrict__ P) {
  const int gid = blockIdx.x * blockDim.x + threadIdx.x;
  const int l = gid & 63;
  int tile = gid >> 6;
  const float* W; int N; unsigned off; int t;
  if      (tile <  288) { W = Wu; N = 384;  off = OFF_WU; t = tile;        }
  else if (tile <  576) { W = Wg; N = 384;  off = OFF_WG; t = tile - 288;  }
  else if (tile <  864) { W = A;  N = 384;  off = OFF_A;  t = tile - 576;  }
  else if (tile < 2016) { W = W1; N = 1536; off = OFF_W1; t = tile - 864;  }
  else if (tile < 3168) { W = W2; N = 384;  off = OFF_W2; t = tile - 2016; }
  else return;
  const int ntn = N >> 4;
  const int kb  = t / ntn, n16 = t % ntn;
  const int krow = kb * 32 + ((l >> 4) << 3);
  const int col  = n16 * 16 + (l & 15);
  us8_t pk;
  #pragma unroll
  for (int j = 0; j < 8; ++j) pk[j] = f2bf(W[(size_t)(krow + j) * N + col]);
  *reinterpret_cast<us8_t*>(P + off + ((size_t)t << 9) + (l << 3)) = pk;
}

// acc[4][3] += A(all 64 LDS rows, swizzled) * B(3 packed k-major tiles)
// #pragma unroll 4 bounds in-flight B loads (12 x 16B) -> no hoisting spills.
template <int NKB>
__device__ __forceinline__ void gemm_acc(const unsigned short* sb,
                                         const unsigned short* __restrict__ bp,
                                         int kb0, int ntn, int n16base,
                                         int lane, f4_t acc[4][3]) {
  const int r    = lane & 15;
  const int sw   = (lane & 7) << 3;
  const int koff = (lane >> 4) << 3;
  #pragma unroll 4
  for (int kb = 0; kb < NKB; ++kb) {
    const int ac = (kb * 32 + koff) ^ sw;
    bf8_t a[4];
    #pragma unroll
    for (int mt = 0; mt < 4; ++mt)
      a[mt] = *reinterpret_cast<const bf8_t*>(&sb[(mt * 16 + r) * CCH + ac]);
    const unsigned short* bt =
        bp + (((size_t)((kb0 + kb) * ntn + n16base) << 9) + (lane << 3));
    #pragma unroll
    for (int nt = 0; nt < 3; ++nt) {
      const bf8_t b = *reinterpret_cast<const bf8_t*>(bt + (nt << 9));
      #pragma unroll
      for (int mt = 0; mt < 4; ++mt)
        acc[mt][nt] = __builtin_amdgcn_mfma_f32_16x16x32_bf16(a[mt], b, acc[mt][nt], 0, 0, 0);
    }
  }
}

// write C/D-layout wave tile (64 x 48, f32 regs) into swizzled bf16 LDS tile
__device__ __forceinline__ void write_tile(unsigned short* sb, const f4_t t[4][3],
                                           int nw, int lane) {
  const int cb = nw * 48 + (lane & 15);
  #pragma unroll
  for (int mt = 0; mt < 4; ++mt)
    #pragma unroll
    for (int j = 0; j < 4; ++j) {
      const int row = mt * 16 + ((lane >> 4) << 2) + j;
      const int sw = (row & 7) << 3;
      #pragma unroll
      for (int nt = 0; nt < 3; ++nt)
        sb[row * CCH + ((cb + nt * 16) ^ sw)] = f2bf(t[mt][nt][j]);
    }
}

__device__ __forceinline__ void zero_acc(f4_t a[4][3]) {
  #pragma unroll
  for (int mt = 0; mt < 4; ++mt)
    #pragma unroll
    for (int nt = 0; nt < 3; ++nt) a[mt][nt] = (f4_t){0.f, 0.f, 0.f, 0.f};
}

__global__ __launch_bounds__(NTHR, 1) void cssm_main(
    const float* __restrict__ x,
    const float* __restrict__ n1s, const float* __restrict__ n1b,
    const float* __restrict__ bu, const float* __restrict__ bg,
    const float* __restrict__ n2s, const float* __restrict__ n2b,
    const float* __restrict__ b1, const float* __restrict__ b2,
    const unsigned short* __restrict__ wp,
    float* __restrict__ out) {
  __shared__ unsigned short sm[3 * HBUF];   // bA | bB | bC
  unsigned short* bA = sm;                  // xn -> h even -> xn2
  unsigned short* bB = sm + HBUF;           // h odd -> m tiles
  unsigned short* bC = sm + 2 * HBUF;       // h8 (persists to Phase E)

  const int tid = threadIdx.x;
  const int lane = tid & 63;
  const int nw = tid >> 6;                  // wave n-slot: cols nw*48..+47
  const int r0 = blockIdx.x * BMROWS;

  // ---------------- Phase A: LN1(x) -> bA (bf16, swizzled) ----------------
  {
    const int row = tid >> 3, seg = tid & 7;
    const float* xr = x + (size_t)(r0 + row) * CCH + seg * 48;
    float v[48];
    float s = 0.f, s2 = 0.f;
    #pragma unroll
    for (int i = 0; i < 12; ++i) {
      const f4_t t = reinterpret_cast<const f4_t*>(xr)[i];
      #pragma unroll
      for (int j = 0; j < 4; ++j) { const float f = t[j]; v[i * 4 + j] = f; s += f; s2 += f * f; }
    }
    #pragma unroll
    for (int o = 1; o < 8; o <<= 1) { s += __shfl_xor(s, o, 64); s2 += __shfl_xor(s2, o, 64); }
    const float mu = s * (1.f / CCH);
    const float rs = rsqrtf(fmaxf(s2 * (1.f / CCH) - mu * mu, 0.f) + LNEPS);
    const int sw = (row & 7) << 3;
    #pragma unroll
    for (int g8 = 0; g8 < 6; ++g8) {
      us8_t pk;
      #pragma unroll
      for (int j = 0; j < 8; ++j) {
        const int colc = seg * 48 + g8 * 8 + j;
        pk[j] = f2bf((v[g8 * 8 + j] - mu) * rs * n1s[colc] + n1b[colc]);
      }
      *reinterpret_cast<us8_t*>(&bA[row * CCH + ((seg * 48 + g8 * 8) ^ sw)]) = pk;
    }
  }
  __syncthreads();

  // ---------------- Phase A2: g, c -> packed-bf16 registers ----------------
  f4_t acc[4][3];
  unsigned gp[4][3][2], cp[4][3][2];
  zero_acc(acc);
  gemm_acc<12>(bA, wp + OFF_WG, 0, 24, nw * 3, lane, acc);
  #pragma unroll
  for (int nt = 0; nt < 3; ++nt) {
    const float bgv = bg[nw * 48 + nt * 16 + (lane & 15)];
    #pragma unroll
    for (int mt = 0; mt < 4; ++mt)
      #pragma unroll
      for (int p = 0; p < 2; ++p)
        gp[mt][nt][p] = pack2(fsigmoid(acc[mt][nt][2 * p] + bgv),
                              fsigmoid(acc[mt][nt][2 * p + 1] + bgv));
  }
  zero_acc(acc);
  gemm_acc<12>(bA, wp + OFF_WU, 0, 24, nw * 3, lane, acc);
  #pragma unroll
  for (int nt = 0; nt < 3; ++nt) {
    const float buv = bu[nw * 48 + nt * 16 + (lane & 15)];
    #pragma unroll
    for (int mt = 0; mt < 4; ++mt)
      #pragma unroll
      for (int p = 0; p < 2; ++p) {
        const unsigned g = gp[mt][nt][p];
        const float c0 = (1.f - ulo(g)) * (acc[mt][nt][2 * p] + buv);
        const float c1 = (1.f - uhi(g)) * (acc[mt][nt][2 * p + 1] + buv);
        acc[mt][nt][2 * p] = c0; acc[mt][nt][2 * p + 1] = c1;
        cp[mt][nt][p] = pack2(c0, c1);
      }
  }
  write_tile(bB, acc, nw, lane);            // h1 = c (bA still being read: ok)
  __syncthreads();

  // ---------------- Phase B: h' = g*(h@A) + c, ping-pong bA/bB -------------
  {
    unsigned short* cur = bB;
    unsigned short* alt = bA;
    #pragma unroll 1
    for (int stp = 0; stp < 7; ++stp) {     // h2..h8
      zero_acc(acc);
      gemm_acc<12>(cur, wp + OFF_A, 0, 24, nw * 3, lane, acc);
      #pragma unroll
      for (int mt = 0; mt < 4; ++mt)
        #pragma unroll
        for (int nt = 0; nt < 3; ++nt)
          #pragma unroll
          for (int p = 0; p < 2; ++p) {
            const unsigned g = gp[mt][nt][p], c = cp[mt][nt][p];
            acc[mt][nt][2 * p]     = ulo(g) * acc[mt][nt][2 * p]     + ulo(c);
            acc[mt][nt][2 * p + 1] = uhi(g) * acc[mt][nt][2 * p + 1] + uhi(c);
          }
      if (stp < 6) {
        write_tile(alt, acc, nw, lane);     // write buffer nobody is reading
        unsigned short* t = cur; cur = alt; alt = t;
        __syncthreads();
      }
    }
    write_tile(bC, acc, nw, lane);          // h8
    __syncthreads();
  }

  // ---------------- Phase C: LN2(x + h8) -> xn2 in bA ----------------------
  {
    const int row = tid >> 3, seg = tid & 7;
    const int sw = (row & 7) << 3;
    const float* xr = x + (size_t)(r0 + row) * CCH + seg * 48;
    float v[48];
    float s = 0.f, s2 = 0.f;
    #pragma unroll
    for (int g8 = 0; g8 < 6; ++g8) {
      const us8_t hv = *reinterpret_cast<const us8_t*>(&bC[row * CCH + ((seg * 48 + g8 * 8) ^ sw)]);
      const f4_t xa = reinterpret_cast<const f4_t*>(xr)[g8 * 2];
      const f4_t xb = reinterpret_cast<const f4_t*>(xr)[g8 * 2 + 1];
      #pragma unroll
      for (int j = 0; j < 4; ++j) {
        const float f0 = xa[j] + bf2f(hv[j]);     v[g8 * 8 + j]     = f0; s += f0; s2 += f0 * f0;
        const float f1 = xb[j] + bf2f(hv[4 + j]); v[g8 * 8 + 4 + j] = f1; s += f1; s2 += f1 * f1;
      }
    }
    #pragma unroll
    for (int o = 1; o < 8; o <<= 1) { s += __shfl_xor(s, o, 64); s2 += __shfl_xor(s2, o, 64); }
    const float mu = s * (1.f / CCH);
    const float rs = rsqrtf(fmaxf(s2 * (1.f / CCH) - mu * mu, 0.f) + LNEPS);
    #pragma unroll
    for (int g8 = 0; g8 < 6; ++g8) {
      us8_t pk;
      #pragma unroll
      for (int j = 0; j < 8; ++j) {
        const int colc = seg * 48 + g8 * 8 + j;
        pk[j] = f2bf((v[g8 * 8 + j] - mu) * rs * n2s[colc] + n2b[colc]);
      }
      *reinterpret_cast<us8_t*>(&bA[row * CCH + ((seg * 48 + g8 * 8) ^ sw)]) = pk;
    }
  }
  __syncthreads();

  // ---------------- Phase D: MLP in 4 HID-chunks of 384 --------------------
  f4_t aco[4][3];
  zero_acc(aco);
  #pragma unroll 1
  for (int ch = 0; ch < 4; ++ch) {
    f4_t am[4][3];
    zero_acc(am);
    gemm_acc<12>(bA, wp + OFF_W1, 0, 96, ch * 24 + nw * 3, lane, am);
    #pragma unroll
    for (int nt = 0; nt < 3; ++nt) {
      const float b1v = b1[ch * 384 + nw * 48 + nt * 16 + (lane & 15)];
      #pragma unroll
      for (int mt = 0; mt < 4; ++mt)
        #pragma unroll
        for (int j = 0; j < 4; ++j) {
          // gelu(z) = z * sigmoid(1.595769122*(z + 0.044715 z^3))  (tanh form)
          const float z = am[mt][nt][j] + b1v;
          const float w = 1.5957691216057308f * (z + 0.044715f * z * z * z);
          am[mt][nt][j] = z * fsigmoid(w);
        }
    }
    if (ch > 0) __syncthreads();            // prev W2-gemm readers of bB done
    write_tile(bB, am, nw, lane);
    __syncthreads();
    gemm_acc<12>(bB, wp + OFF_W2, ch * 12, 24, nw * 3, lane, aco);
  }

  // ---------------- Phase E: out = x + h8 + mlp + b2 -----------------------
  #pragma unroll
  for (int nt = 0; nt < 3; ++nt) {
    const int col = nw * 48 + nt * 16 + (lane & 15);
    const float b2v = b2[col];
    #pragma unroll
    for (int mt = 0; mt < 4; ++mt)
      #pragma unroll
      for (int j = 0; j < 4; ++j) {
        const int row = mt * 16 + ((lane >> 4) << 2) + j;
        const float hv = bf2f(bC[row * CCH + (col ^ ((row & 7) << 3))]);
        out[(size_t)(r0 + row) * CCH + col] =
            x[(size_t)(r0 + row) * CCH + col] + hv + aco[mt][nt][j] + b2v;
      }
  }
}

extern "C" void kernel_launch(void* const* d_in, const int* in_sizes, int n_in,
                              void* d_out, int out_size, void* d_ws, size_t ws_size,
                              hipStream_t stream) {
  const float* x   = (const float*)d_in[0];
  const float* n1s = (const float*)d_in[1];
  const float* n1b = (const float*)d_in[2];
  const float* Wu  = (const float*)d_in[3];
  const float* bu  = (const float*)d_in[4];
  const float* Wg  = (const float*)d_in[5];
  const float* bg  = (const float*)d_in[6];
  const float* A   = (const float*)d_in[7];
  const float* n2s = (const float*)d_in[8];
  const float* n2b = (const float*)d_in[9];
  const float* W1  = (const float*)d_in[10];
  const float* b1  = (const float*)d_in[11];
  const float* W2  = (const float*)d_in[12];
  const float* b2  = (const float*)d_in[13];
  unsigned short* wp = (unsigned short*)d_ws;
  float* out = (float*)d_out;

  // pack all weights to bf16 fragment order (one launch; 3168 tiles * 64 lanes)
  pack_all<<<(3168 * 64) / 256, 256, 0, stream>>>(Wu, Wg, A, W1, W2, wp);

  cssm_main<<<NPIX / BMROWS, NTHR, 0, stream>>>(
      x, n1s, n1b, bu, bg, n2s, n2b, b1, b2, wp, out);
}